// Round 10
// baseline (249.365 us; speedup 1.0000x reference)
//
#include <hip/hip_runtime.h>
#include <hip/hip_bf16.h>
#include <stdint.h>

#define DM 768
#define SQ 4096
#define NH 12

typedef __bf16 bf16;
typedef __bf16 bf16x8 __attribute__((ext_vector_type(8)));
typedef float floatx4 __attribute__((ext_vector_type(4)));
typedef short short4v __attribute__((ext_vector_type(4)));

#if defined(__has_builtin)
#if __has_builtin(__builtin_amdgcn_mfma_f32_16x16x16bf16_1k)
#define HAVE_MFMA16 1
#endif
#endif
#ifndef HAVE_MFMA16
#define HAVE_MFMA16 0
#endif

typedef __attribute__((address_space(1))) const uint32_t cu32_g;
typedef __attribute__((address_space(3))) uint32_t u32_l;

__device__ __forceinline__ uint16_t f2bf(float f) {
  uint32_t u = __builtin_bit_cast(uint32_t, f);
  u += 0x7fff + ((u >> 16) & 1);
  return (uint16_t)(u >> 16);
}

// RNE bf16 pair pack (precision-verified in rounds 5-8; do NOT replace with
// round-half-up — round 9 showed it costs ~4x absmax).
__device__ __forceinline__ uint32_t pk2(float lo, float hi) {
  __hip_bfloat162 h = __float22bfloat162_rn(float2{lo, hi});
  uint32_t u;
  __builtin_memcpy(&u, &h, 4);
  return u;
}

// async global->LDS, 16B/lane; LDS dst is wave-uniform base, lane i -> base+i*16
__device__ __forceinline__ void async16(const bf16* g, bf16* l) {
  __builtin_amdgcn_global_load_lds((cu32_g*)g, (u32_l*)l, 16, 0, 0);
}

// ---------------- convert fp32 -> bf16 ----------------
__global__ __launch_bounds__(256) void cvt_kernel(
    const float* __restrict__ x, const float* __restrict__ wq,
    const float* __restrict__ wk, const float* __restrict__ wv,
    const float* __restrict__ wp, bf16* __restrict__ xb, bf16* __restrict__ wqb,
    bf16* __restrict__ wkb, bf16* __restrict__ wvb, bf16* __restrict__ wpb) {
  const int XQ = (SQ * DM) / 4;
  const int WQ = (DM * DM) / 4;
  int t = blockIdx.x * 256 + threadIdx.x;
  const float* src;
  bf16* dst;
  int local;
  if (t < XQ) { src = x;  dst = xb;  local = t; }
  else if (t < XQ + WQ)     { src = wq; dst = wqb; local = t - XQ; }
  else if (t < XQ + 2 * WQ) { src = wk; dst = wkb; local = t - XQ - WQ; }
  else if (t < XQ + 3 * WQ) { src = wv; dst = wvb; local = t - XQ - 2 * WQ; }
  else                      { src = wp; dst = wpb; local = t - XQ - 3 * WQ; }
  float4 v = ((const float4*)src)[local];
  ushort4 o;
  o.x = f2bf(v.x); o.y = f2bf(v.y); o.z = f2bf(v.z); o.w = f2bf(v.w);
  ((ushort4*)dst)[local] = o;
}

// ---------------- NT GEMM core 128x128, double-buffered staging -----------
__device__ __forceinline__ void gemm_core(const bf16* __restrict__ A,
                                          const bf16* __restrict__ B, int m0,
                                          int n0, floatx4 (&acc)[4][4]) {
  __shared__ bf16 lA[2 * 4096];
  __shared__ bf16 lB[2 * 4096];
  const int tid = threadIdx.x;
  const int lane = tid & 63;
  const int w = tid >> 6;

  const int r0 = w * 32 + (lane >> 2);
  const int ke = (((lane & 3) ^ ((lane >> 3) & 3))) * 8;  // swizzled src chunk
  const bf16* gA0 = A + (size_t)(m0 + r0) * DM + ke;
  const bf16* gA1 = A + (size_t)(m0 + r0 + 16) * DM + ke;
  const bf16* gB0 = B + (size_t)(n0 + r0) * DM + ke;
  const bf16* gB1 = B + (size_t)(n0 + r0 + 16) * DM + ke;

  // prologue: stage kt=0 into buf 0
  async16(gA0, lA + w * 1024); async16(gA1, lA + w * 1024 + 512);
  async16(gB0, lB + w * 1024); async16(gB1, lB + w * 1024 + 512);
  gA0 += 32; gA1 += 32; gB0 += 32; gB1 += 32;

  const int mrow = (w >> 1) * 64 + (lane & 15);
  const int nrow = (w & 1) * 64 + (lane & 15);
  const int cswz = ((lane >> 4) ^ ((lane >> 1) & 3)) * 8;  // swizzled read chunk

  for (int kt = 0; kt < DM / 32; ++kt) {
    __syncthreads();  // drains loads issued last iter (full iter of cover)
    if (kt + 1 < DM / 32) {
      const int nb = ((kt + 1) & 1) * 4096;
      async16(gA0, lA + nb + w * 1024); async16(gA1, lA + nb + w * 1024 + 512);
      async16(gB0, lB + nb + w * 1024); async16(gB1, lB + nb + w * 1024 + 512);
      gA0 += 32; gA1 += 32; gB0 += 32; gB1 += 32;
    }
    const int cb = (kt & 1) * 4096;
    bf16x8 a[4], b[4];
#pragma unroll
    for (int mt = 0; mt < 4; ++mt)
      a[mt] = *(const bf16x8*)&lA[cb + (mrow + mt * 16) * 32 + cswz];
#pragma unroll
    for (int nt = 0; nt < 4; ++nt)
      b[nt] = *(const bf16x8*)&lB[cb + (nrow + nt * 16) * 32 + cswz];
#pragma unroll
    for (int mt = 0; mt < 4; ++mt)
#pragma unroll
      for (int nt = 0; nt < 4; ++nt)
        acc[mt][nt] = __builtin_amdgcn_mfma_f32_16x16x32_bf16(
            a[mt], b[nt], acc[mt][nt], 0, 0, 0);
  }
}

// QKV: z=0 -> Q (pre-scaled by 0.125*log2e); z=1 -> K; z=2 -> V^T
__global__ __launch_bounds__(256) void qkv_kernel(
    const bf16* __restrict__ xb, const bf16* __restrict__ wq,
    const bf16* __restrict__ wk, const bf16* __restrict__ wv,
    bf16* __restrict__ Qb, bf16* __restrict__ Kb, bf16* __restrict__ Vtb) {
  const int z = blockIdx.z;
  const bf16* B = (z == 0) ? wq : (z == 1) ? wk : wv;
  const int m0 = blockIdx.x * 128, n0 = blockIdx.y * 128;
  floatx4 acc[4][4] = {};
  gemm_core(xb, B, m0, n0, acc);
  const int lane = threadIdx.x & 63, w = threadIdx.x >> 6;
  const int quad = lane >> 4, ql = lane & 15;
  const float qs = (z == 0) ? 0.18033688011112042f : 1.0f;  // 0.125*log2(e)
  if (z < 2) {
    bf16* C = (z == 0) ? Qb : Kb;
#pragma unroll
    for (int mt = 0; mt < 4; ++mt)
#pragma unroll
      for (int nt = 0; nt < 4; ++nt) {
        int row = m0 + (w >> 1) * 64 + mt * 16 + quad * 4;
        int col = n0 + (w & 1) * 64 + nt * 16 + ql;
#pragma unroll
        for (int r = 0; r < 4; ++r)
          *(uint16_t*)&C[(size_t)(row + r) * DM + col] = f2bf(acc[mt][nt][r] * qs);
      }
  } else {
#pragma unroll
    for (int mt = 0; mt < 4; ++mt)
#pragma unroll
      for (int nt = 0; nt < 4; ++nt) {
        int row = m0 + (w >> 1) * 64 + mt * 16 + quad * 4;  // s
        int col = n0 + (w & 1) * 64 + nt * 16 + ql;         // d
        uint32_t lo = pk2(acc[mt][nt][0], acc[mt][nt][1]);
        uint32_t hi = pk2(acc[mt][nt][2], acc[mt][nt][3]);
        *(uint2*)&Vtb[(size_t)col * SQ + row] = make_uint2(lo, hi);
      }
  }
}

// output projection, 64x128 tiles (384 blocks), double-buffered staging.
// A = attention output: read unnormalized fp32 O-sums + L from the atomic
// buffers, normalize (exact IEEE divide) and pack bf16 during staging
// (replaces the old combine kernel + Ob round-trip entirely).
__global__ __launch_bounds__(256) void proj_kernel(
    const float* __restrict__ Of, const float* __restrict__ Lf,
    const bf16* __restrict__ wp, float* __restrict__ out) {
  __shared__ bf16 lA[2 * 2048];
  __shared__ bf16 lB[2 * 4096];
  const int tid = threadIdx.x, lane = tid & 63, w = tid >> 6;
  const int m0 = blockIdx.x * 64, n0 = blockIdx.y * 128;

  const int ke = (((lane & 3) ^ ((lane >> 3) & 3))) * 8;  // swizzled src chunk
  const int r0v = w * 16 + (lane >> 2);                   // A row in tile
  const float* gA = Of + (size_t)(m0 + r0v) * DM + ke;    // fp32 O-sums
  const float* gL = Lf + (size_t)(m0 + r0v) * NH;
  const bf16* gB0 = wp + (size_t)(n0 + w * 32 + (lane >> 2)) * DM + ke;
  const bf16* gB1 = wp + (size_t)(n0 + w * 32 + (lane >> 2) + 16) * DM + ke;

  // prologue: stage kt=0 into buf 0
  async16(gB0, lB + w * 1024); async16(gB1, lB + w * 1024 + 512);
  gB0 += 32; gB1 += 32;
  {
    float4 a0 = *(const float4*)gA;
    float4 a1 = *(const float4*)(gA + 4);
    float rl = 1.0f / gL[ke >> 6];  // exact divide (rcp cost precision, r9)
    uint4 u;
    u.x = pk2(a0.x * rl, a0.y * rl); u.y = pk2(a0.z * rl, a0.w * rl);
    u.z = pk2(a1.x * rl, a1.y * rl); u.w = pk2(a1.z * rl, a1.w * rl);
    *(uint4*)&lA[tid * 8] = u;  // writer addr degenerates to tid*8: conflict-free
  }

  const int mrow = (w >> 1) * 32 + (lane & 15);
  const int nrow = (w & 1) * 64 + (lane & 15);
  const int cswz = ((lane >> 4) ^ ((lane >> 1) & 3)) * 8;
  floatx4 acc[2][4] = {};

  for (int kt = 0; kt < DM / 32; ++kt) {
    __syncthreads();  // staged (kt) visible
    float4 a0, a1;
    float rl;
    const bool more = (kt + 1 < DM / 32);
    if (more) {
      const int nbB = ((kt + 1) & 1) * 4096;
      async16(gB0, lB + nbB + w * 1024); async16(gB1, lB + nbB + w * 1024 + 512);
      gB0 += 32; gB1 += 32;
      int d0 = (kt + 1) * 32 + ke;
      a0 = *(const float4*)(gA + (kt + 1) * 32);
      a1 = *(const float4*)(gA + (kt + 1) * 32 + 4);
      rl = 1.0f / gL[d0 >> 6];
    }
    const int cbA = (kt & 1) * 2048, cbB = (kt & 1) * 4096;
    bf16x8 a[2], b[4];
#pragma unroll
    for (int mt = 0; mt < 2; ++mt)
      a[mt] = *(const bf16x8*)&lA[cbA + (mrow + mt * 16) * 32 + cswz];
#pragma unroll
    for (int nt = 0; nt < 4; ++nt)
      b[nt] = *(const bf16x8*)&lB[cbB + (nrow + nt * 16) * 32 + cswz];
#pragma unroll
    for (int mt = 0; mt < 2; ++mt)
#pragma unroll
      for (int nt = 0; nt < 4; ++nt)
        acc[mt][nt] = __builtin_amdgcn_mfma_f32_16x16x32_bf16(
            a[mt], b[nt], acc[mt][nt], 0, 0, 0);
    if (more) {
      const int nbA = ((kt + 1) & 1) * 2048;
      uint4 u;
      u.x = pk2(a0.x * rl, a0.y * rl); u.y = pk2(a0.z * rl, a0.w * rl);
      u.z = pk2(a1.x * rl, a1.y * rl); u.w = pk2(a1.z * rl, a1.w * rl);
      *(uint4*)&lA[nbA + tid * 8] = u;
    }
  }
  const int quad = lane >> 4, ql = lane & 15;
#pragma unroll
  for (int mt = 0; mt < 2; ++mt)
#pragma unroll
    for (int nt = 0; nt < 4; ++nt) {
      int row = m0 + (w >> 1) * 32 + mt * 16 + quad * 4;
      int col = n0 + (w & 1) * 64 + nt * 16 + ql;
#pragma unroll
      for (int r = 0; r < 4; ++r)
        out[(size_t)(row + r) * DM + col] = acc[mt][nt][r];
    }
}

// ---------------- split-KV causal flash attention (transposed) ------------
// K+V double-buffered (64 KB). Fixed-base softmax: partials are PLAIN SUMS,
// so blocks atomically accumulate unnormalized fp32 O and L; proj divides.
__global__ __launch_bounds__(256) void attn_kernel(
    const bf16* __restrict__ Qb, const bf16* __restrict__ Kb,
    const bf16* __restrict__ Vtb, float* __restrict__ Of,
    float* __restrict__ Lf) {
#if HAVE_MFMA16
  __shared__ __align__(16) char smem[65536];
#else
  __shared__ __align__(16) char smem[73728];
  bf16* lPt = (bf16*)(smem + 65536);  // 8 KB per-wave P^T scratch
#endif
  const int tid = threadIdx.x, lane = tid & 63, w = tid >> 6;
  const int quad = lane >> 4, ql = lane & 15;

  // heavy-first mapping, head-interleaved: i=0..79 per head
  int b = blockIdx.x;
  int h = b % NH;
  int i = b / NH;
  int qb, c;
  if (i < 32)      { qb = 31 - (i >> 2); c = i & 3; }
  else if (i < 56) { int t2 = i - 32; qb = 23 - t2 / 3; c = t2 % 3; }
  else if (i < 72) { int t2 = i - 56; qb = 15 - (t2 >> 1); c = t2 & 1; }
  else             { qb = 79 - i; c = 0; }
  const int kv0 = c * 1024;
  const int kv_end = min((qb + 1) * 128, kv0 + 1024);
  const int n_it = (kv_end - kv0) >> 7;
  const bool diag = (kv_end == (qb + 1) * 128);

  // Q fragments (pre-scaled), B-operand layout
  bf16x8 qf[2][2];
#pragma unroll
  for (int nt = 0; nt < 2; ++nt)
#pragma unroll
    for (int kt = 0; kt < 2; ++kt)
      qf[nt][kt] = *(const bf16x8*)&Qb[(size_t)(qb * 128 + w * 32 + nt * 16 + ql) * DM +
                                       h * 64 + kt * 32 + quad * 8];

  // staging pointers (source-side XOR chunk swizzle)
  const int src_e = (((lane & 3) ^ ((lane >> 3) & 3))) * 8;
  const bf16* gK[4];
  const bf16* gV4[4];
#pragma unroll
  for (int t = 0; t < 4; ++t) {
    int o = t * 4096 + w * 1024 + lane * 16;  // byte in 16KB K image
    int cK = o >> 13, rK = (o & 8191) >> 6;
    gK[t] = Kb + (size_t)(kv0 + rK) * DM + h * 64 + cK * 32 + src_e;
    int dV = w * 16 + (lane >> 2);            // V image: [t][dV][32]
    gV4[t] = Vtb + (size_t)(h * 64 + dV) * SQ + kv0 + t * 32 + src_e;
  }

  // prologue: stage K(0)+V(0) into buf 0
#pragma unroll
  for (int t = 0; t < 4; ++t) {
    async16(gK[t], (bf16*)(smem + t * 4096 + w * 1024));
    async16(gV4[t], (bf16*)(smem + 16384 + t * 4096 + w * 1024));
    gK[t] += 128 * DM;
    gV4[t] += 128;
  }

  floatx4 o_acc[4][2] = {};
  float l_s[2] = {0.f, 0.f};  // per-lane partial (reduced once in epilogue)
  const int cswz = ((lane >> 4) ^ ((lane >> 1) & 3)) * 8;

  for (int j = 0; j < n_it; ++j) {
    __syncthreads();  // drains (j) tiles staged last iter: full iter of cover
    if (j + 1 < n_it) {
      char* dst = smem + ((j + 1) & 1) * 32768;
#pragma unroll
      for (int t = 0; t < 4; ++t) {
        async16(gK[t], (bf16*)(dst + t * 4096 + w * 1024));
        async16(gV4[t], (bf16*)(dst + 16384 + t * 4096 + w * 1024));
        gK[t] += 128 * DM;
        gV4[t] += 128;
      }
    }
    const char* cbuf = smem + (j & 1) * 32768;
    const bf16* kbuf = (const bf16*)cbuf;
    const char* vbuf = cbuf + 16384;

    floatx4 s[8][2] = {};
#pragma unroll
    for (int kt = 0; kt < 2; ++kt)
#pragma unroll
      for (int mt = 0; mt < 8; ++mt) {
        bf16x8 a = *(const bf16x8*)&kbuf[kt * 4096 + (mt * 16 + ql) * 32 + cswz];
#pragma unroll
        for (int nt = 0; nt < 2; ++nt)
          s[mt][nt] = __builtin_amdgcn_mfma_f32_16x16x32_bf16(a, qf[nt][kt],
                                                              s[mt][nt], 0, 0, 0);
      }

    if (diag && j == n_it - 1) {
#pragma unroll
      for (int mt = 0; mt < 8; ++mt)
#pragma unroll
        for (int nt = 0; nt < 2; ++nt)
#pragma unroll
          for (int r = 0; r < 4; ++r) {
            int kpos = mt * 16 + quad * 4 + r;
            int qpos = w * 32 + nt * 16 + ql;
            if (kpos > qpos) s[mt][nt][r] = -1e30f;
          }
    }

    // fixed-base softmax: exp2 + RNE pack + tree-sum, one pass
    uint2 pp[8][2];
#pragma unroll
    for (int nt = 0; nt < 2; ++nt) {
      float tsum[8];
#pragma unroll
      for (int mt = 0; mt < 8; ++mt) {
        float p0 = __builtin_amdgcn_exp2f(s[mt][nt][0]);
        float p1 = __builtin_amdgcn_exp2f(s[mt][nt][1]);
        float p2 = __builtin_amdgcn_exp2f(s[mt][nt][2]);
        float p3 = __builtin_amdgcn_exp2f(s[mt][nt][3]);
        pp[mt][nt] = make_uint2(pk2(p0, p1), pk2(p2, p3));
        tsum[mt] = (p0 + p1) + (p2 + p3);
      }
      l_s[nt] += ((tsum[0] + tsum[1]) + (tsum[2] + tsum[3])) +
                 ((tsum[4] + tsum[5]) + (tsum[6] + tsum[7]));
    }

#if HAVE_MFMA16
    // PV: O^T[d][q] += V^T · P^T, P^T B-frags straight from packed regs
#pragma unroll
    for (int mt = 0; mt < 8; ++mt) {
      short4v bfr[2];
#pragma unroll
      for (int nt = 0; nt < 2; ++nt) {
        union { uint2 u; short4v v; } pb;
        pb.u = pp[mt][nt];
        bfr[nt] = pb.v;
      }
      const char* vbase = vbuf + (mt >> 1) * 4096 +
          ((((mt & 1) * 2 + (quad >> 1)) ^ ((ql >> 1) & 3)) * 16) +
          (quad & 1) * 8;
#pragma unroll
      for (int mtd = 0; mtd < 4; ++mtd) {
        short4v a = *(const short4v*)(vbase + (mtd * 16 + ql) * 64);
#pragma unroll
        for (int nt = 0; nt < 2; ++nt)
          o_acc[mtd][nt] = __builtin_amdgcn_mfma_f32_16x16x16bf16_1k(
              a, bfr[nt], o_acc[mtd][nt], 0, 0, 0);
      }
    }
#else
    bf16* lp = lPt + w * 1024;  // wave-private
#pragma unroll
    for (int ks = 0; ks < 4; ++ks) {
#pragma unroll
      for (int nt = 0; nt < 2; ++nt) {
        int q32 = nt * 16 + ql;
        int key = (q32 >> 1) & 7;
#pragma unroll
        for (int mtp = 0; mtp < 2; ++mtp) {
          int slot = mtp * 4 + quad;
          *(uint2*)((char*)lp + q32 * 64 + ((slot ^ key) * 8)) = pp[2 * ks + mtp][nt];
        }
      }
      bf16x8 bp[2];
#pragma unroll
      for (int nt = 0; nt < 2; ++nt) {
        int q32 = nt * 16 + ql;
        int key = (q32 >> 1) & 7;
        union { uint2 u[2]; bf16x8 v; } pb;
        pb.u[0] = *(uint2*)((char*)lp + q32 * 64 + (((2 * quad) ^ key) * 8));
        pb.u[1] = *(uint2*)((char*)lp + q32 * 64 + (((2 * quad + 1) ^ key) * 8));
        bp[nt] = pb.v;
      }
#pragma unroll
      for (int mtd = 0; mtd < 4; ++mtd) {
        bf16x8 a = *(const bf16x8*)((const bf16*)vbuf + ks * 2048 +
                                    (mtd * 16 + ql) * 32 + cswz);
#pragma unroll
        for (int nt = 0; nt < 2; ++nt)
          o_acc[mtd][nt] = __builtin_amdgcn_mfma_f32_16x16x32_bf16(
              a, bp[nt], o_acc[mtd][nt], 0, 0, 0);
      }
    }
#endif
  }

  // finalize l across the 4 lane-groups; accumulate partials via atomics
  float lf[2];
#pragma unroll
  for (int nt = 0; nt < 2; ++nt) {
    float ls = l_s[nt];
    ls += __shfl_xor(ls, 16);
    ls += __shfl_xor(ls, 32);
    lf[nt] = ls;
  }

#pragma unroll
  for (int nt = 0; nt < 2; ++nt) {
    int qg = qb * 128 + w * 32 + nt * 16 + ql;
    if (quad == 0) atomicAdd(&Lf[qg * NH + h], lf[nt]);
#pragma unroll
    for (int mtd = 0; mtd < 4; ++mtd) {
      float* dst = &Of[(size_t)qg * DM + h * 64 + mtd * 16 + quad * 4];
      atomicAdd(dst + 0, o_acc[mtd][nt][0]);
      atomicAdd(dst + 1, o_acc[mtd][nt][1]);
      atomicAdd(dst + 2, o_acc[mtd][nt][2]);
      atomicAdd(dst + 3, o_acc[mtd][nt][3]);
    }
  }
}

extern "C" void kernel_launch(void* const* d_in, const int* in_sizes, int n_in,
                              void* d_out, int out_size, void* d_ws,
                              size_t ws_size, hipStream_t stream) {
  const float* x  = (const float*)d_in[0];
  const float* wq = (const float*)d_in[1];
  const float* wk = (const float*)d_in[2];
  const float* wv = (const float*)d_in[3];
  const float* wp = (const float*)d_in[4];
  char* ws = (char*)d_ws;
  bf16* xb   = (bf16*)(ws);
  bf16* wqb  = (bf16*)(ws + 6291456);
  bf16* wkb  = (bf16*)(ws + 7471104);
  bf16* wvb  = (bf16*)(ws + 8650752);
  bf16* wpb  = (bf16*)(ws + 9830400);
  bf16* Qb   = (bf16*)(ws + 11010048);
  bf16* Kb   = (bf16*)(ws + 17301504);
  bf16* Vtb  = (bf16*)(ws + 23592960);
  float* Of  = (float*)(ws + 36175872);  // fp32 O accumulator, 12.58 MB
  float* Lf  = (float*)(ws + 48758784);  // fp32 L accumulator, 192 KB

  hipMemsetAsync(ws + 36175872, 0, 12582912 + 196608, stream);  // zero Of+Lf
  cvt_kernel<<<5376, 256, 0, stream>>>(x, wq, wk, wv, wp, xb, wqb, wkb, wvb, wpb);
  qkv_kernel<<<dim3(32, 6, 3), 256, 0, stream>>>(xb, wqb, wkb, wvb, Qb, Kb, Vtb);
  attn_kernel<<<960, 256, 0, stream>>>(Qb, Kb, Vtb, Of, Lf);
  proj_kernel<<<dim3(64, 6), 256, 0, stream>>>(Of, Lf, wpb, (float*)d_out);
}

// Round 11
// 198.149 us; speedup vs baseline: 1.2585x; 1.2585x over previous
//
#include <hip/hip_runtime.h>
#include <hip/hip_bf16.h>
#include <stdint.h>

#define DM 768
#define SQ 4096
#define NH 12

typedef __bf16 bf16;
typedef __bf16 bf16x8 __attribute__((ext_vector_type(8)));
typedef float floatx4 __attribute__((ext_vector_type(4)));
typedef short short4v __attribute__((ext_vector_type(4)));

#if defined(__has_builtin)
#if __has_builtin(__builtin_amdgcn_mfma_f32_16x16x16bf16_1k)
#define HAVE_MFMA16 1
#endif
#endif
#ifndef HAVE_MFMA16
#define HAVE_MFMA16 0
#endif

typedef __attribute__((address_space(1))) const uint32_t cu32_g;
typedef __attribute__((address_space(3))) uint32_t u32_l;

__device__ __forceinline__ uint16_t f2bf(float f) {
  uint32_t u = __builtin_bit_cast(uint32_t, f);
  u += 0x7fff + ((u >> 16) & 1);
  return (uint16_t)(u >> 16);
}

// RNE bf16 pair pack (precision-proven r5-r8; round-half-up costs 4x absmax, r9)
__device__ __forceinline__ uint32_t pk2(float lo, float hi) {
  __hip_bfloat162 h = __float22bfloat162_rn(float2{lo, hi});
  uint32_t u;
  __builtin_memcpy(&u, &h, 4);
  return u;
}

__device__ __forceinline__ float bflo(uint32_t u) {
  return __builtin_bit_cast(float, u << 16);
}
__device__ __forceinline__ float bfhi(uint32_t u) {
  return __builtin_bit_cast(float, u & 0xffff0000u);
}

// async global->LDS, 16B/lane; LDS dst is wave-uniform base, lane i -> base+i*16
__device__ __forceinline__ void async16(const bf16* g, bf16* l) {
  __builtin_amdgcn_global_load_lds((cu32_g*)g, (u32_l*)l, 16, 0, 0);
}

// ---------------- convert fp32 -> bf16 ----------------
__global__ __launch_bounds__(256) void cvt_kernel(
    const float* __restrict__ x, const float* __restrict__ wq,
    const float* __restrict__ wk, const float* __restrict__ wv,
    const float* __restrict__ wp, bf16* __restrict__ xb, bf16* __restrict__ wqb,
    bf16* __restrict__ wkb, bf16* __restrict__ wvb, bf16* __restrict__ wpb) {
  const int XQ = (SQ * DM) / 4;
  const int WQ = (DM * DM) / 4;
  int t = blockIdx.x * 256 + threadIdx.x;
  const float* src;
  bf16* dst;
  int local;
  if (t < XQ) { src = x;  dst = xb;  local = t; }
  else if (t < XQ + WQ)     { src = wq; dst = wqb; local = t - XQ; }
  else if (t < XQ + 2 * WQ) { src = wk; dst = wkb; local = t - XQ - WQ; }
  else if (t < XQ + 3 * WQ) { src = wv; dst = wvb; local = t - XQ - 2 * WQ; }
  else                      { src = wp; dst = wpb; local = t - XQ - 3 * WQ; }
  float4 v = ((const float4*)src)[local];
  ushort4 o;
  o.x = f2bf(v.x); o.y = f2bf(v.y); o.z = f2bf(v.z); o.w = f2bf(v.w);
  ((ushort4*)dst)[local] = o;
}

// ---------------- NT GEMM core 128x128, double-buffered staging -----------
__device__ __forceinline__ void gemm_core(const bf16* __restrict__ A,
                                          const bf16* __restrict__ B, int m0,
                                          int n0, floatx4 (&acc)[4][4]) {
  __shared__ bf16 lA[2 * 4096];
  __shared__ bf16 lB[2 * 4096];
  const int tid = threadIdx.x;
  const int lane = tid & 63;
  const int w = tid >> 6;

  const int r0 = w * 32 + (lane >> 2);
  const int ke = (((lane & 3) ^ ((lane >> 3) & 3))) * 8;  // swizzled src chunk
  const bf16* gA0 = A + (size_t)(m0 + r0) * DM + ke;
  const bf16* gA1 = A + (size_t)(m0 + r0 + 16) * DM + ke;
  const bf16* gB0 = B + (size_t)(n0 + r0) * DM + ke;
  const bf16* gB1 = B + (size_t)(n0 + r0 + 16) * DM + ke;

  // prologue: stage kt=0 into buf 0
  async16(gA0, lA + w * 1024); async16(gA1, lA + w * 1024 + 512);
  async16(gB0, lB + w * 1024); async16(gB1, lB + w * 1024 + 512);
  gA0 += 32; gA1 += 32; gB0 += 32; gB1 += 32;

  const int mrow = (w >> 1) * 64 + (lane & 15);
  const int nrow = (w & 1) * 64 + (lane & 15);
  const int cswz = ((lane >> 4) ^ ((lane >> 1) & 3)) * 8;  // swizzled read chunk

  for (int kt = 0; kt < DM / 32; ++kt) {
    __syncthreads();  // drains loads issued last iter (full iter of cover)
    if (kt + 1 < DM / 32) {
      const int nb = ((kt + 1) & 1) * 4096;
      async16(gA0, lA + nb + w * 1024); async16(gA1, lA + nb + w * 1024 + 512);
      async16(gB0, lB + nb + w * 1024); async16(gB1, lB + nb + w * 1024 + 512);
      gA0 += 32; gA1 += 32; gB0 += 32; gB1 += 32;
    }
    const int cb = (kt & 1) * 4096;
    bf16x8 a[4], b[4];
#pragma unroll
    for (int mt = 0; mt < 4; ++mt)
      a[mt] = *(const bf16x8*)&lA[cb + (mrow + mt * 16) * 32 + cswz];
#pragma unroll
    for (int nt = 0; nt < 4; ++nt)
      b[nt] = *(const bf16x8*)&lB[cb + (nrow + nt * 16) * 32 + cswz];
#pragma unroll
    for (int mt = 0; mt < 4; ++mt)
#pragma unroll
      for (int nt = 0; nt < 4; ++nt)
        acc[mt][nt] = __builtin_amdgcn_mfma_f32_16x16x32_bf16(
            a[mt], b[nt], acc[mt][nt], 0, 0, 0);
  }
}

// QKV: z=0 -> Q (pre-scaled by 0.125*log2e); z=1 -> K; z=2 -> V^T
__global__ __launch_bounds__(256) void qkv_kernel(
    const bf16* __restrict__ xb, const bf16* __restrict__ wq,
    const bf16* __restrict__ wk, const bf16* __restrict__ wv,
    bf16* __restrict__ Qb, bf16* __restrict__ Kb, bf16* __restrict__ Vtb) {
  const int z = blockIdx.z;
  const bf16* B = (z == 0) ? wq : (z == 1) ? wk : wv;
  const int m0 = blockIdx.x * 128, n0 = blockIdx.y * 128;
  floatx4 acc[4][4] = {};
  gemm_core(xb, B, m0, n0, acc);
  const int lane = threadIdx.x & 63, w = threadIdx.x >> 6;
  const int quad = lane >> 4, ql = lane & 15;
  const float qs = (z == 0) ? 0.18033688011112042f : 1.0f;  // 0.125*log2(e)
  if (z < 2) {
    bf16* C = (z == 0) ? Qb : Kb;
#pragma unroll
    for (int mt = 0; mt < 4; ++mt)
#pragma unroll
      for (int nt = 0; nt < 4; ++nt) {
        int row = m0 + (w >> 1) * 64 + mt * 16 + quad * 4;
        int col = n0 + (w & 1) * 64 + nt * 16 + ql;
#pragma unroll
        for (int r = 0; r < 4; ++r)
          *(uint16_t*)&C[(size_t)(row + r) * DM + col] = f2bf(acc[mt][nt][r] * qs);
      }
  } else {
#pragma unroll
    for (int mt = 0; mt < 4; ++mt)
#pragma unroll
      for (int nt = 0; nt < 4; ++nt) {
        int row = m0 + (w >> 1) * 64 + mt * 16 + quad * 4;  // s
        int col = n0 + (w & 1) * 64 + nt * 16 + ql;         // d
        uint32_t lo = pk2(acc[mt][nt][0], acc[mt][nt][1]);
        uint32_t hi = pk2(acc[mt][nt][2], acc[mt][nt][3]);
        *(uint2*)&Vtb[(size_t)col * SQ + row] = make_uint2(lo, hi);
      }
  }
}

// output projection, 64x128 tiles (384 blocks), double-buffered B staging.
// A-staging fuses the old combine kernel: merge <=4 bf16 partial chunks +
// per-head L sums (fixed-base softmax -> plain sums), normalize, pack to the
// swizzled LDS image (writer addr tid*8: conflict-free; layout proven r10).
__global__ __launch_bounds__(256) void proj_kernel(
    const uint16_t* __restrict__ OpartB, const float* __restrict__ Lpart,
    const bf16* __restrict__ wp, float* __restrict__ out) {
  __shared__ bf16 lA[2 * 2048];
  __shared__ bf16 lB[2 * 4096];
  const int tid = threadIdx.x, lane = tid & 63, w = tid >> 6;
  const int m0 = blockIdx.x * 64, n0 = blockIdx.y * 128;

  const int ke = (((lane & 3) ^ ((lane >> 3) & 3))) * 8;  // swizzled src chunk
  const int r0v = w * 16 + (lane >> 2);                   // A row in tile
  const int qg = m0 + r0v;
  const int qb = qg >> 7, qloc = qg & 127;
  const int nch = (qb + 8) >> 3;  // 1..4 chunks to merge (block-uniform)
  const bf16* gB0 = wp + (size_t)(n0 + w * 32 + (lane >> 2)) * DM + ke;
  const bf16* gB1 = wp + (size_t)(n0 + w * 32 + (lane >> 2) + 16) * DM + ke;

  // precompute 1/L per head (exact divide; rcp cost precision in r9)
  float rlh[NH];
#pragma unroll
  for (int h = 0; h < NH; ++h) {
    int ps0 = (h * 32 + qb) * 4;
    float L = 0.f;
#pragma unroll
    for (int cc = 0; cc < 4; ++cc)
      if (cc < nch) L += Lpart[(ps0 + cc) * 128 + qloc];
    rlh[h] = 1.0f / L;
  }

  // prologue: stage kt=0 into buf 0
  async16(gB0, lB + w * 1024); async16(gB1, lB + w * 1024 + 512);
  gB0 += 32; gB1 += 32;
  {
    const int h = 0, dh = ke;
    const int ps0 = (h * 32 + qb) * 4;
    float acc8[8] = {};
#pragma unroll
    for (int cc = 0; cc < 4; ++cc)
      if (cc < nch) {
        uint4 u = *(const uint4*)&OpartB[(size_t)(ps0 + cc) * 8192 + qloc * 64 + dh];
        acc8[0] += bflo(u.x); acc8[1] += bfhi(u.x);
        acc8[2] += bflo(u.y); acc8[3] += bfhi(u.y);
        acc8[4] += bflo(u.z); acc8[5] += bfhi(u.z);
        acc8[6] += bflo(u.w); acc8[7] += bfhi(u.w);
      }
    float rl = rlh[0];
    uint4 o;
    o.x = pk2(acc8[0] * rl, acc8[1] * rl); o.y = pk2(acc8[2] * rl, acc8[3] * rl);
    o.z = pk2(acc8[4] * rl, acc8[5] * rl); o.w = pk2(acc8[6] * rl, acc8[7] * rl);
    *(uint4*)&lA[tid * 8] = o;
  }

  const int mrow = (w >> 1) * 32 + (lane & 15);
  const int nrow = (w & 1) * 64 + (lane & 15);
  const int cswz = ((lane >> 4) ^ ((lane >> 1) & 3)) * 8;
  floatx4 acc[2][4] = {};

  for (int kt = 0; kt < DM / 32; ++kt) {
    __syncthreads();  // staged (kt) visible
    const bool more = (kt + 1 < DM / 32);
    float acc8[8] = {};
    float rl = 0.f;
    if (more) {
      const int nbB = ((kt + 1) & 1) * 4096;
      async16(gB0, lB + nbB + w * 1024); async16(gB1, lB + nbB + w * 1024 + 512);
      gB0 += 32; gB1 += 32;
      const int h = (kt + 1) >> 1;
      const int dh = ((kt + 1) & 1) * 32 + ke;
      const int ps0 = (h * 32 + qb) * 4;
#pragma unroll
      for (int cc = 0; cc < 4; ++cc)
        if (cc < nch) {
          uint4 u = *(const uint4*)&OpartB[(size_t)(ps0 + cc) * 8192 + qloc * 64 + dh];
          acc8[0] += bflo(u.x); acc8[1] += bfhi(u.x);
          acc8[2] += bflo(u.y); acc8[3] += bfhi(u.y);
          acc8[4] += bflo(u.z); acc8[5] += bfhi(u.z);
          acc8[6] += bflo(u.w); acc8[7] += bfhi(u.w);
        }
      rl = rlh[h];
    }
    const int cbA = (kt & 1) * 2048, cbB = (kt & 1) * 4096;
    bf16x8 a[2], b[4];
#pragma unroll
    for (int mt = 0; mt < 2; ++mt)
      a[mt] = *(const bf16x8*)&lA[cbA + (mrow + mt * 16) * 32 + cswz];
#pragma unroll
    for (int nt = 0; nt < 4; ++nt)
      b[nt] = *(const bf16x8*)&lB[cbB + (nrow + nt * 16) * 32 + cswz];
#pragma unroll
    for (int mt = 0; mt < 2; ++mt)
#pragma unroll
      for (int nt = 0; nt < 4; ++nt)
        acc[mt][nt] = __builtin_amdgcn_mfma_f32_16x16x32_bf16(
            a[mt], b[nt], acc[mt][nt], 0, 0, 0);
    if (more) {
      const int nbA = ((kt + 1) & 1) * 2048;
      uint4 o;
      o.x = pk2(acc8[0] * rl, acc8[1] * rl); o.y = pk2(acc8[2] * rl, acc8[3] * rl);
      o.z = pk2(acc8[4] * rl, acc8[5] * rl); o.w = pk2(acc8[6] * rl, acc8[7] * rl);
      *(uint4*)&lA[nbA + tid * 8] = o;
    }
  }
  const int quad = lane >> 4, ql = lane & 15;
#pragma unroll
  for (int mt = 0; mt < 2; ++mt)
#pragma unroll
    for (int nt = 0; nt < 4; ++nt) {
      int row = m0 + (w >> 1) * 32 + mt * 16 + quad * 4;
      int col = n0 + (w & 1) * 64 + nt * 16 + ql;
#pragma unroll
      for (int r = 0; r < 4; ++r)
        out[(size_t)(row + r) * DM + col] = acc[mt][nt][r];
    }
}

// ---------------- split-KV causal flash attention (transposed) ------------
// K+V double-buffered (64 KB). Fixed-base softmax; every block writes its
// chunk's plain-sum partials (packed bf16) + L. NO global atomics (r10: fp32
// atomicAdd epilogue cost 8x WRITE_SIZE and 2.2x duration).
__global__ __launch_bounds__(256) void attn_kernel(
    const bf16* __restrict__ Qb, const bf16* __restrict__ Kb,
    const bf16* __restrict__ Vtb, uint16_t* __restrict__ OpartB,
    float* __restrict__ Lpart) {
#if HAVE_MFMA16
  __shared__ __align__(16) char smem[65536];
#else
  __shared__ __align__(16) char smem[73728];
  bf16* lPt = (bf16*)(smem + 65536);  // 8 KB per-wave P^T scratch
#endif
  const int tid = threadIdx.x, lane = tid & 63, w = tid >> 6;
  const int quad = lane >> 4, ql = lane & 15;

  // heavy-first mapping, head-interleaved: i=0..79 per head
  int b = blockIdx.x;
  int h = b % NH;
  int i = b / NH;
  int qb, c;
  if (i < 32)      { qb = 31 - (i >> 2); c = i & 3; }
  else if (i < 56) { int t2 = i - 32; qb = 23 - t2 / 3; c = t2 % 3; }
  else if (i < 72) { int t2 = i - 56; qb = 15 - (t2 >> 1); c = t2 & 1; }
  else             { qb = 79 - i; c = 0; }
  const int kv0 = c * 1024;
  const int kv_end = min((qb + 1) * 128, kv0 + 1024);
  const int n_it = (kv_end - kv0) >> 7;

  // Q fragments (pre-scaled), B-operand layout
  bf16x8 qf[2][2];
#pragma unroll
  for (int nt = 0; nt < 2; ++nt)
#pragma unroll
    for (int kt = 0; kt < 2; ++kt)
      qf[nt][kt] = *(const bf16x8*)&Qb[(size_t)(qb * 128 + w * 32 + nt * 16 + ql) * DM +
                                       h * 64 + kt * 32 + quad * 8];

  // staging pointers (source-side XOR chunk swizzle)
  const int src_e = (((lane & 3) ^ ((lane >> 3) & 3))) * 8;
  const bf16* gK[4];
  const bf16* gV4[4];
#pragma unroll
  for (int t = 0; t < 4; ++t) {
    int o = t * 4096 + w * 1024 + lane * 16;  // byte in 16KB K image
    int cK = o >> 13, rK = (o & 8191) >> 6;
    gK[t] = Kb + (size_t)(kv0 + rK) * DM + h * 64 + cK * 32 + src_e;
    int dV = w * 16 + (lane >> 2);            // V image: [t][dV][32]
    gV4[t] = Vtb + (size_t)(h * 64 + dV) * SQ + kv0 + t * 32 + src_e;
  }

  // prologue: stage K(0)+V(0) into buf 0
#pragma unroll
  for (int t = 0; t < 4; ++t) {
    async16(gK[t], (bf16*)(smem + t * 4096 + w * 1024));
    async16(gV4[t], (bf16*)(smem + 16384 + t * 4096 + w * 1024));
    gK[t] += 128 * DM;
    gV4[t] += 128;
  }

  floatx4 o_acc[4][2] = {};
  float l_s[2] = {0.f, 0.f};  // per-lane partial (reduced once in epilogue)
  const int cswz = ((lane >> 4) ^ ((lane >> 1) & 3)) * 8;
  const bool diag = (kv_end == (qb + 1) * 128);

  for (int j = 0; j < n_it; ++j) {
    __syncthreads();  // drains (j) tiles staged last iter: full iter of cover
    if (j + 1 < n_it) {
      char* dst = smem + ((j + 1) & 1) * 32768;
#pragma unroll
      for (int t = 0; t < 4; ++t) {
        async16(gK[t], (bf16*)(dst + t * 4096 + w * 1024));
        async16(gV4[t], (bf16*)(dst + 16384 + t * 4096 + w * 1024));
        gK[t] += 128 * DM;
        gV4[t] += 128;
      }
    }
    const char* cbuf = smem + (j & 1) * 32768;
    const bf16* kbuf = (const bf16*)cbuf;
    const char* vbuf = cbuf + 16384;

    floatx4 s[8][2] = {};
#pragma unroll
    for (int kt = 0; kt < 2; ++kt)
#pragma unroll
      for (int mt = 0; mt < 8; ++mt) {
        bf16x8 a = *(const bf16x8*)&kbuf[kt * 4096 + (mt * 16 + ql) * 32 + cswz];
#pragma unroll
        for (int nt = 0; nt < 2; ++nt)
          s[mt][nt] = __builtin_amdgcn_mfma_f32_16x16x32_bf16(a, qf[nt][kt],
                                                              s[mt][nt], 0, 0, 0);
      }

    if (diag && j == n_it - 1) {
#pragma unroll
      for (int mt = 0; mt < 8; ++mt)
#pragma unroll
        for (int nt = 0; nt < 2; ++nt)
#pragma unroll
          for (int r = 0; r < 4; ++r) {
            int kpos = mt * 16 + quad * 4 + r;
            int qpos = w * 32 + nt * 16 + ql;
            if (kpos > qpos) s[mt][nt][r] = -1e30f;
          }
    }

    // fixed-base softmax: exp2 + RNE pack + tree-sum, one pass
    uint2 pp[8][2];
#pragma unroll
    for (int nt = 0; nt < 2; ++nt) {
      float tsum[8];
#pragma unroll
      for (int mt = 0; mt < 8; ++mt) {
        float p0 = __builtin_amdgcn_exp2f(s[mt][nt][0]);
        float p1 = __builtin_amdgcn_exp2f(s[mt][nt][1]);
        float p2 = __builtin_amdgcn_exp2f(s[mt][nt][2]);
        float p3 = __builtin_amdgcn_exp2f(s[mt][nt][3]);
        pp[mt][nt] = make_uint2(pk2(p0, p1), pk2(p2, p3));
        tsum[mt] = (p0 + p1) + (p2 + p3);
      }
      l_s[nt] += ((tsum[0] + tsum[1]) + (tsum[2] + tsum[3])) +
                 ((tsum[4] + tsum[5]) + (tsum[6] + tsum[7]));
    }

#if HAVE_MFMA16
    // PV: O^T[d][q] += V^T · P^T, P^T B-frags straight from packed regs
#pragma unroll
    for (int mt = 0; mt < 8; ++mt) {
      short4v bfr[2];
#pragma unroll
      for (int nt = 0; nt < 2; ++nt) {
        union { uint2 u; short4v v; } pb;
        pb.u = pp[mt][nt];
        bfr[nt] = pb.v;
      }
      const char* vbase = vbuf + (mt >> 1) * 4096 +
          ((((mt & 1) * 2 + (quad >> 1)) ^ ((ql >> 1) & 3)) * 16) +
          (quad & 1) * 8;
#pragma unroll
      for (int mtd = 0; mtd < 4; ++mtd) {
        short4v a = *(const short4v*)(vbase + (mtd * 16 + ql) * 64);
#pragma unroll
        for (int nt = 0; nt < 2; ++nt)
          o_acc[mtd][nt] = __builtin_amdgcn_mfma_f32_16x16x16bf16_1k(
              a, bfr[nt], o_acc[mtd][nt], 0, 0, 0);
      }
    }
#else
    bf16* lp = lPt + w * 1024;  // wave-private
#pragma unroll
    for (int ks = 0; ks < 4; ++ks) {
#pragma unroll
      for (int nt = 0; nt < 2; ++nt) {
        int q32 = nt * 16 + ql;
        int key = (q32 >> 1) & 7;
#pragma unroll
        for (int mtp = 0; mtp < 2; ++mtp) {
          int slot = mtp * 4 + quad;
          *(uint2*)((char*)lp + q32 * 64 + ((slot ^ key) * 8)) = pp[2 * ks + mtp][nt];
        }
      }
      bf16x8 bp[2];
#pragma unroll
      for (int nt = 0; nt < 2; ++nt) {
        int q32 = nt * 16 + ql;
        int key = (q32 >> 1) & 7;
        union { uint2 u[2]; bf16x8 v; } pb;
        pb.u[0] = *(uint2*)((char*)lp + q32 * 64 + (((2 * quad) ^ key) * 8));
        pb.u[1] = *(uint2*)((char*)lp + q32 * 64 + (((2 * quad + 1) ^ key) * 8));
        bp[nt] = pb.v;
      }
#pragma unroll
      for (int mtd = 0; mtd < 4; ++mtd) {
        bf16x8 a = *(const bf16x8*)((const bf16*)vbuf + ks * 2048 +
                                    (mtd * 16 + ql) * 32 + cswz);
#pragma unroll
        for (int nt = 0; nt < 2; ++nt)
          o_acc[mtd][nt] = __builtin_amdgcn_mfma_f32_16x16x32_bf16(
              a, bp[nt], o_acc[mtd][nt], 0, 0, 0);
      }
    }
#endif
  }

  // finalize l across the 4 lane-groups; write packed bf16 partials + L
  float lf[2];
#pragma unroll
  for (int nt = 0; nt < 2; ++nt) {
    float ls = l_s[nt];
    ls += __shfl_xor(ls, 16);
    ls += __shfl_xor(ls, 32);
    lf[nt] = ls;
  }

  const int ps = (h * 32 + qb) * 4 + c;
#pragma unroll
  for (int nt = 0; nt < 2; ++nt) {
    int q = w * 32 + nt * 16 + ql;
    if (quad == 0) Lpart[ps * 128 + q] = lf[nt];
#pragma unroll
    for (int mtd = 0; mtd < 4; ++mtd) {
      uint32_t lo = pk2(o_acc[mtd][nt][0], o_acc[mtd][nt][1]);
      uint32_t hi = pk2(o_acc[mtd][nt][2], o_acc[mtd][nt][3]);
      *(uint2*)&OpartB[(size_t)ps * 8192 + q * 64 + mtd * 16 + quad * 4] =
          make_uint2(lo, hi);
    }
  }
}

extern "C" void kernel_launch(void* const* d_in, const int* in_sizes, int n_in,
                              void* d_out, int out_size, void* d_ws,
                              size_t ws_size, hipStream_t stream) {
  const float* x  = (const float*)d_in[0];
  const float* wq = (const float*)d_in[1];
  const float* wk = (const float*)d_in[2];
  const float* wv = (const float*)d_in[3];
  const float* wp = (const float*)d_in[4];
  char* ws = (char*)d_ws;
  // Lpart lives in the xb region (dead after qkv; attn writes before proj
  // reads). Peak ws usage = 61341696 B (round-5..8-proven size).
  float* Lpart = (float*)(ws);             // 1536*128*4 = 786432 (inside xb)
  bf16* xb   = (bf16*)(ws);
  bf16* wqb  = (bf16*)(ws + 6291456);
  bf16* wkb  = (bf16*)(ws + 7471104);
  bf16* wvb  = (bf16*)(ws + 8650752);
  bf16* wpb  = (bf16*)(ws + 9830400);
  bf16* Qb   = (bf16*)(ws + 11010048);
  bf16* Kb   = (bf16*)(ws + 17301504);
  bf16* Vtb  = (bf16*)(ws + 23592960);
  uint16_t* OpartB = (uint16_t*)(ws + 36175872);  // 1536 x 8192 bf16 -> 61341696

  cvt_kernel<<<5376, 256, 0, stream>>>(x, wq, wk, wv, wp, xb, wqb, wkb, wvb, wpb);
  qkv_kernel<<<dim3(32, 6, 3), 256, 0, stream>>>(xb, wqb, wkb, wvb, Qb, Kb, Vtb);
  attn_kernel<<<960, 256, 0, stream>>>(Qb, Kb, Vtb, OpartB, Lpart);
  proj_kernel<<<dim3(64, 6), 256, 0, stream>>>(OpartB, Lpart, wpb, (float*)d_out);
}

// Round 12
// 177.407 us; speedup vs baseline: 1.4056x; 1.1169x over previous
//
#include <hip/hip_runtime.h>
#include <hip/hip_bf16.h>
#include <stdint.h>

#define DM 768
#define SQ 4096
#define NH 12

typedef __bf16 bf16;
typedef __bf16 bf16x8 __attribute__((ext_vector_type(8)));
typedef float floatx4 __attribute__((ext_vector_type(4)));
typedef short short4v __attribute__((ext_vector_type(4)));

#if defined(__has_builtin)
#if __has_builtin(__builtin_amdgcn_mfma_f32_16x16x16bf16_1k)
#define HAVE_MFMA16 1
#endif
#endif
#ifndef HAVE_MFMA16
#define HAVE_MFMA16 0
#endif

typedef __attribute__((address_space(1))) const uint32_t cu32_g;
typedef __attribute__((address_space(3))) uint32_t u32_l;

__device__ __forceinline__ uint16_t f2bf(float f) {
  uint32_t u = __builtin_bit_cast(uint32_t, f);
  u += 0x7fff + ((u >> 16) & 1);
  return (uint16_t)(u >> 16);
}

// RNE bf16 pair pack (precision-proven r5-r8; round-half-up costs 4x absmax, r9)
__device__ __forceinline__ uint32_t pk2(float lo, float hi) {
  __hip_bfloat162 h = __float22bfloat162_rn(float2{lo, hi});
  uint32_t u;
  __builtin_memcpy(&u, &h, 4);
  return u;
}

__device__ __forceinline__ float bflo(uint32_t u) {
  return __builtin_bit_cast(float, u << 16);
}
__device__ __forceinline__ float bfhi(uint32_t u) {
  return __builtin_bit_cast(float, u & 0xffff0000u);
}

// async global->LDS, 16B/lane; LDS dst is wave-uniform base, lane i -> base+i*16
__device__ __forceinline__ void async16(const bf16* g, bf16* l) {
  __builtin_amdgcn_global_load_lds((cu32_g*)g, (u32_l*)l, 16, 0, 0);
}

// ---------------- convert fp32 -> bf16 ----------------
__global__ __launch_bounds__(256) void cvt_kernel(
    const float* __restrict__ x, const float* __restrict__ wq,
    const float* __restrict__ wk, const float* __restrict__ wv,
    const float* __restrict__ wp, bf16* __restrict__ xb, bf16* __restrict__ wqb,
    bf16* __restrict__ wkb, bf16* __restrict__ wvb, bf16* __restrict__ wpb) {
  const int XQ = (SQ * DM) / 4;
  const int WQ = (DM * DM) / 4;
  int t = blockIdx.x * 256 + threadIdx.x;
  const float* src;
  bf16* dst;
  int local;
  if (t < XQ) { src = x;  dst = xb;  local = t; }
  else if (t < XQ + WQ)     { src = wq; dst = wqb; local = t - XQ; }
  else if (t < XQ + 2 * WQ) { src = wk; dst = wkb; local = t - XQ - WQ; }
  else if (t < XQ + 3 * WQ) { src = wv; dst = wvb; local = t - XQ - 2 * WQ; }
  else                      { src = wp; dst = wpb; local = t - XQ - 3 * WQ; }
  float4 v = ((const float4*)src)[local];
  ushort4 o;
  o.x = f2bf(v.x); o.y = f2bf(v.y); o.z = f2bf(v.z); o.w = f2bf(v.w);
  ((ushort4*)dst)[local] = o;
}

// ---------------- NT GEMM core 128x128, double-buffered staging -----------
__device__ __forceinline__ void gemm_core(const bf16* __restrict__ A,
                                          const bf16* __restrict__ B, int m0,
                                          int n0, floatx4 (&acc)[4][4]) {
  __shared__ bf16 lA[2 * 4096];
  __shared__ bf16 lB[2 * 4096];
  const int tid = threadIdx.x;
  const int lane = tid & 63;
  const int w = tid >> 6;

  const int r0 = w * 32 + (lane >> 2);
  const int ke = (((lane & 3) ^ ((lane >> 3) & 3))) * 8;  // swizzled src chunk
  const bf16* gA0 = A + (size_t)(m0 + r0) * DM + ke;
  const bf16* gA1 = A + (size_t)(m0 + r0 + 16) * DM + ke;
  const bf16* gB0 = B + (size_t)(n0 + r0) * DM + ke;
  const bf16* gB1 = B + (size_t)(n0 + r0 + 16) * DM + ke;

  // prologue: stage kt=0 into buf 0
  async16(gA0, lA + w * 1024); async16(gA1, lA + w * 1024 + 512);
  async16(gB0, lB + w * 1024); async16(gB1, lB + w * 1024 + 512);
  gA0 += 32; gA1 += 32; gB0 += 32; gB1 += 32;

  const int mrow = (w >> 1) * 64 + (lane & 15);
  const int nrow = (w & 1) * 64 + (lane & 15);
  const int cswz = ((lane >> 4) ^ ((lane >> 1) & 3)) * 8;  // swizzled read chunk

  for (int kt = 0; kt < DM / 32; ++kt) {
    __syncthreads();  // drains loads issued last iter (full iter of cover)
    if (kt + 1 < DM / 32) {
      const int nb = ((kt + 1) & 1) * 4096;
      async16(gA0, lA + nb + w * 1024); async16(gA1, lA + nb + w * 1024 + 512);
      async16(gB0, lB + nb + w * 1024); async16(gB1, lB + nb + w * 1024 + 512);
      gA0 += 32; gA1 += 32; gB0 += 32; gB1 += 32;
    }
    const int cb = (kt & 1) * 4096;
    bf16x8 a[4], b[4];
#pragma unroll
    for (int mt = 0; mt < 4; ++mt)
      a[mt] = *(const bf16x8*)&lA[cb + (mrow + mt * 16) * 32 + cswz];
#pragma unroll
    for (int nt = 0; nt < 4; ++nt)
      b[nt] = *(const bf16x8*)&lB[cb + (nrow + nt * 16) * 32 + cswz];
#pragma unroll
    for (int mt = 0; mt < 4; ++mt)
#pragma unroll
      for (int nt = 0; nt < 4; ++nt)
        acc[mt][nt] = __builtin_amdgcn_mfma_f32_16x16x32_bf16(
            a[mt], b[nt], acc[mt][nt], 0, 0, 0);
  }
}

// QKV: z=0 -> Q (pre-scaled by 0.125*log2e); z=1 -> K; z=2 -> V^T
__global__ __launch_bounds__(256) void qkv_kernel(
    const bf16* __restrict__ xb, const bf16* __restrict__ wq,
    const bf16* __restrict__ wk, const bf16* __restrict__ wv,
    bf16* __restrict__ Qb, bf16* __restrict__ Kb, bf16* __restrict__ Vtb) {
  const int z = blockIdx.z;
  const bf16* B = (z == 0) ? wq : (z == 1) ? wk : wv;
  const int m0 = blockIdx.x * 128, n0 = blockIdx.y * 128;
  floatx4 acc[4][4] = {};
  gemm_core(xb, B, m0, n0, acc);
  const int lane = threadIdx.x & 63, w = threadIdx.x >> 6;
  const int quad = lane >> 4, ql = lane & 15;
  const float qs = (z == 0) ? 0.18033688011112042f : 1.0f;  // 0.125*log2(e)
  if (z < 2) {
    bf16* C = (z == 0) ? Qb : Kb;
#pragma unroll
    for (int mt = 0; mt < 4; ++mt)
#pragma unroll
      for (int nt = 0; nt < 4; ++nt) {
        int row = m0 + (w >> 1) * 64 + mt * 16 + quad * 4;
        int col = n0 + (w & 1) * 64 + nt * 16 + ql;
#pragma unroll
        for (int r = 0; r < 4; ++r)
          *(uint16_t*)&C[(size_t)(row + r) * DM + col] = f2bf(acc[mt][nt][r] * qs);
      }
  } else {
#pragma unroll
    for (int mt = 0; mt < 4; ++mt)
#pragma unroll
      for (int nt = 0; nt < 4; ++nt) {
        int row = m0 + (w >> 1) * 64 + mt * 16 + quad * 4;  // s
        int col = n0 + (w & 1) * 64 + nt * 16 + ql;         // d
        uint32_t lo = pk2(acc[mt][nt][0], acc[mt][nt][1]);
        uint32_t hi = pk2(acc[mt][nt][2], acc[mt][nt][3]);
        *(uint2*)&Vtb[(size_t)col * SQ + row] = make_uint2(lo, hi);
      }
  }
}

// output projection, 64x128 tiles (384 blocks), double-buffered staging
// (r8-proven: reads merged Ob bf16; fusion of the merge regressed in r11)
__global__ __launch_bounds__(256) void proj_kernel(
    const bf16* __restrict__ Ob, const bf16* __restrict__ wp,
    float* __restrict__ out) {
  __shared__ bf16 lA[2 * 2048];
  __shared__ bf16 lB[2 * 4096];
  const int tid = threadIdx.x, lane = tid & 63, w = tid >> 6;
  const int m0 = blockIdx.x * 64, n0 = blockIdx.y * 128;

  const int ke = (((lane & 3) ^ ((lane >> 3) & 3))) * 8;
  const bf16* gA = Ob + (size_t)(m0 + w * 16 + (lane >> 2)) * DM + ke;
  const bf16* gB0 = wp + (size_t)(n0 + w * 32 + (lane >> 2)) * DM + ke;
  const bf16* gB1 = wp + (size_t)(n0 + w * 32 + (lane >> 2) + 16) * DM + ke;

  // prologue: stage kt=0 into buf 0
  async16(gA, lA + w * 512);
  async16(gB0, lB + w * 1024); async16(gB1, lB + w * 1024 + 512);
  gA += 32; gB0 += 32; gB1 += 32;

  const int mrow = (w >> 1) * 32 + (lane & 15);
  const int nrow = (w & 1) * 64 + (lane & 15);
  const int cswz = ((lane >> 4) ^ ((lane >> 1) & 3)) * 8;
  floatx4 acc[2][4] = {};

  for (int kt = 0; kt < DM / 32; ++kt) {
    __syncthreads();
    if (kt + 1 < DM / 32) {
      const int nbA = ((kt + 1) & 1) * 2048, nbB = ((kt + 1) & 1) * 4096;
      async16(gA, lA + nbA + w * 512);
      async16(gB0, lB + nbB + w * 1024); async16(gB1, lB + nbB + w * 1024 + 512);
      gA += 32; gB0 += 32; gB1 += 32;
    }
    const int cbA = (kt & 1) * 2048, cbB = (kt & 1) * 4096;
    bf16x8 a[2], b[4];
#pragma unroll
    for (int mt = 0; mt < 2; ++mt)
      a[mt] = *(const bf16x8*)&lA[cbA + (mrow + mt * 16) * 32 + cswz];
#pragma unroll
    for (int nt = 0; nt < 4; ++nt)
      b[nt] = *(const bf16x8*)&lB[cbB + (nrow + nt * 16) * 32 + cswz];
#pragma unroll
    for (int mt = 0; mt < 2; ++mt)
#pragma unroll
      for (int nt = 0; nt < 4; ++nt)
        acc[mt][nt] = __builtin_amdgcn_mfma_f32_16x16x32_bf16(
            a[mt], b[nt], acc[mt][nt], 0, 0, 0);
  }
  const int quad = lane >> 4, ql = lane & 15;
#pragma unroll
  for (int mt = 0; mt < 2; ++mt)
#pragma unroll
    for (int nt = 0; nt < 4; ++nt) {
      int row = m0 + (w >> 1) * 32 + mt * 16 + quad * 4;
      int col = n0 + (w & 1) * 64 + nt * 16 + ql;
#pragma unroll
      for (int r = 0; r < 4; ++r)
        out[(size_t)(row + r) * DM + col] = acc[mt][nt][r];
    }
}

// ---------------- split-KV causal flash attention (transposed) ------------
// kv-tile = 64 (was 128): LDS = 2 x (8KB K + 8KB V) = 32 KB -> 5 blocks/CU,
// all 960 blocks co-resident. Per-iter work halves, iters double; numerics
// order-identical to r8. K+V double-buffered, one barrier/iter, no mid-iter
// vmcnt. Fixed-base softmax (Q pre-scaled): p = exp2(s), plain-sum partials.
__global__ __launch_bounds__(256) void attn_kernel(
    const bf16* __restrict__ Qb, const bf16* __restrict__ Kb,
    const bf16* __restrict__ Vtb, uint16_t* __restrict__ OpartB,
    float* __restrict__ Lpart, bf16* __restrict__ Ob) {
#if HAVE_MFMA16
  __shared__ __align__(16) char smem[32768];
#else
  __shared__ __align__(16) char smem[40960];
  bf16* lPt = (bf16*)(smem + 32768);  // 8 KB per-wave P^T scratch
#endif
  // buffer b at smem + b*16384: K = 8 KB ([2 dchunk][64 kv][32 d-elems]),
  // V = 8 KB at +8192 ([2 kvchunk][64 d][32 kv]); both source-swizzled.
  const int tid = threadIdx.x, lane = tid & 63, w = tid >> 6;
  const int quad = lane >> 4, ql = lane & 15;

  // heavy-first mapping, head-interleaved: i=0..79 per head
  int b = blockIdx.x;
  int h = b % NH;
  int i = b / NH;
  int qb, c;
  if (i < 32)      { qb = 31 - (i >> 2); c = i & 3; }
  else if (i < 56) { int t2 = i - 32; qb = 23 - t2 / 3; c = t2 % 3; }
  else if (i < 72) { int t2 = i - 56; qb = 15 - (t2 >> 1); c = t2 & 1; }
  else             { qb = 79 - i; c = 0; }
  const int kv0 = c * 1024;
  const int kv_end = min((qb + 1) * 128, kv0 + 1024);
  const int n_it = (kv_end - kv0) >> 6;  // kv-tiles of 64
  const bool diag = (kv_end == (qb + 1) * 128);

  // Q fragments (pre-scaled), B-operand layout
  bf16x8 qf[2][2];
#pragma unroll
  for (int nt = 0; nt < 2; ++nt)
#pragma unroll
    for (int kt = 0; kt < 2; ++kt)
      qf[nt][kt] = *(const bf16x8*)&Qb[(size_t)(qb * 128 + w * 32 + nt * 16 + ql) * DM +
                                       h * 64 + kt * 32 + quad * 8];

  // staging pointers (source-side XOR chunk swizzle); t spans 2 chunks
  const int src_e = (((lane & 3) ^ ((lane >> 3) & 3))) * 8;
  const bf16* gK[2];
  const bf16* gV[2];
#pragma unroll
  for (int t = 0; t < 2; ++t) {
    int o = t * 4096 + w * 1024 + lane * 16;  // byte in 8KB image
    int rr = (o & 4095) >> 6;                 // row within chunk (0..63)
    gK[t] = Kb + (size_t)(kv0 + rr) * DM + h * 64 + t * 32 + src_e;
    gV[t] = Vtb + (size_t)(h * 64 + rr) * SQ + kv0 + t * 32 + src_e;
  }

  // prologue: stage K(0)+V(0) into buf 0
#pragma unroll
  for (int t = 0; t < 2; ++t) {
    async16(gK[t], (bf16*)(smem + t * 4096 + w * 1024));
    async16(gV[t], (bf16*)(smem + 8192 + t * 4096 + w * 1024));
    gK[t] += 64 * DM;
    gV[t] += 64;
  }

  floatx4 o_acc[4][2] = {};
  float l_s[2] = {0.f, 0.f};  // per-lane partial (reduced once in epilogue)
  const int cswz = ((lane >> 4) ^ ((lane >> 1) & 3)) * 8;

  for (int j = 0; j < n_it; ++j) {
    __syncthreads();  // drains (j) tiles staged last iter: full iter of cover
    if (j + 1 < n_it) {
      char* dst = smem + ((j + 1) & 1) * 16384;
#pragma unroll
      for (int t = 0; t < 2; ++t) {
        async16(gK[t], (bf16*)(dst + t * 4096 + w * 1024));
        async16(gV[t], (bf16*)(dst + 8192 + t * 4096 + w * 1024));
        gK[t] += 64 * DM;
        gV[t] += 64;
      }
    }
    const char* cbuf = smem + (j & 1) * 16384;
    const bf16* kbuf = (const bf16*)cbuf;
    const char* vbuf = cbuf + 8192;

    // S^T[kv 64][q 32] = K . Q^T
    floatx4 s[4][2] = {};
#pragma unroll
    for (int kt = 0; kt < 2; ++kt)
#pragma unroll
      for (int mt = 0; mt < 4; ++mt) {
        bf16x8 a = *(const bf16x8*)&kbuf[kt * 2048 + (mt * 16 + ql) * 32 + cswz];
#pragma unroll
        for (int nt = 0; nt < 2; ++nt)
          s[mt][nt] = __builtin_amdgcn_mfma_f32_16x16x32_bf16(a, qf[nt][kt],
                                                              s[mt][nt], 0, 0, 0);
      }

    if (diag && j + 2 >= n_it) {  // last two 64-tiles straddle the diagonal
      const int kbase = kv0 + j * 64;
#pragma unroll
      for (int mt = 0; mt < 4; ++mt)
#pragma unroll
        for (int nt = 0; nt < 2; ++nt)
#pragma unroll
          for (int r = 0; r < 4; ++r) {
            int kabs = kbase + mt * 16 + quad * 4 + r;
            int qabs = qb * 128 + w * 32 + nt * 16 + ql;
            if (kabs > qabs) s[mt][nt][r] = -1e30f;
          }
    }

    // fixed-base softmax: exp2 + RNE pack + tree-sum, one pass
    uint2 pp[4][2];
#pragma unroll
    for (int nt = 0; nt < 2; ++nt) {
      float tsum[4];
#pragma unroll
      for (int mt = 0; mt < 4; ++mt) {
        float p0 = __builtin_amdgcn_exp2f(s[mt][nt][0]);
        float p1 = __builtin_amdgcn_exp2f(s[mt][nt][1]);
        float p2 = __builtin_amdgcn_exp2f(s[mt][nt][2]);
        float p3 = __builtin_amdgcn_exp2f(s[mt][nt][3]);
        pp[mt][nt] = make_uint2(pk2(p0, p1), pk2(p2, p3));
        tsum[mt] = (p0 + p1) + (p2 + p3);
      }
      l_s[nt] += (tsum[0] + tsum[1]) + (tsum[2] + tsum[3]);
    }

#if HAVE_MFMA16
    // PV: O^T[d][q] += V^T . P^T, P^T B-frags straight from packed regs
#pragma unroll
    for (int mt = 0; mt < 4; ++mt) {
      short4v bfr[2];
#pragma unroll
      for (int nt = 0; nt < 2; ++nt) {
        union { uint2 u; short4v v; } pb;
        pb.u = pp[mt][nt];
        bfr[nt] = pb.v;
      }
      const char* vbase = vbuf + (mt >> 1) * 4096 +
          ((((mt & 1) * 2 + (quad >> 1)) ^ ((ql >> 1) & 3)) * 16) +
          (quad & 1) * 8;
#pragma unroll
      for (int mtd = 0; mtd < 4; ++mtd) {
        short4v a = *(const short4v*)(vbase + (mtd * 16 + ql) * 64);
#pragma unroll
        for (int nt = 0; nt < 2; ++nt)
          o_acc[mtd][nt] = __builtin_amdgcn_mfma_f32_16x16x16bf16_1k(
              a, bfr[nt], o_acc[mtd][nt], 0, 0, 0);
      }
    }
#else
    bf16* lp = lPt + w * 1024;  // wave-private
#pragma unroll
    for (int ks = 0; ks < 2; ++ks) {
#pragma unroll
      for (int nt = 0; nt < 2; ++nt) {
        int q32 = nt * 16 + ql;
        int key = (q32 >> 1) & 7;
#pragma unroll
        for (int mtp = 0; mtp < 2; ++mtp) {
          int slot = mtp * 4 + quad;
          *(uint2*)((char*)lp + q32 * 64 + ((slot ^ key) * 8)) = pp[2 * ks + mtp][nt];
        }
      }
      bf16x8 bp[2];
#pragma unroll
      for (int nt = 0; nt < 2; ++nt) {
        int q32 = nt * 16 + ql;
        int key = (q32 >> 1) & 7;
        union { uint2 u[2]; bf16x8 v; } pb;
        pb.u[0] = *(uint2*)((char*)lp + q32 * 64 + (((2 * quad) ^ key) * 8));
        pb.u[1] = *(uint2*)((char*)lp + q32 * 64 + (((2 * quad + 1) ^ key) * 8));
        bp[nt] = pb.v;
      }
#pragma unroll
      for (int mtd = 0; mtd < 4; ++mtd) {
        bf16x8 a = *(const bf16x8*)((const bf16*)vbuf + ks * 2048 +
                                    (mtd * 16 + ql) * 32 + cswz);
#pragma unroll
        for (int nt = 0; nt < 2; ++nt)
          o_acc[mtd][nt] = __builtin_amdgcn_mfma_f32_16x16x32_bf16(
              a, bp[nt], o_acc[mtd][nt], 0, 0, 0);
      }
    }
#endif
  }

  // finalize l across the 4 lane-groups (once, not per iter)
  float lf[2];
#pragma unroll
  for (int nt = 0; nt < 2; ++nt) {
    float ls = l_s[nt];
    ls += __shfl_xor(ls, 16);
    ls += __shfl_xor(ls, 32);
    lf[nt] = ls;
  }

  if (kv0 == 0 && diag) {
    // single-chunk tile: normalized direct store
#pragma unroll
    for (int nt = 0; nt < 2; ++nt) {
      float rl = 1.0f / lf[nt];
      int qg = qb * 128 + w * 32 + nt * 16 + ql;
#pragma unroll
      for (int mtd = 0; mtd < 4; ++mtd) {
        uint32_t lo = pk2(o_acc[mtd][nt][0] * rl, o_acc[mtd][nt][1] * rl);
        uint32_t hi = pk2(o_acc[mtd][nt][2] * rl, o_acc[mtd][nt][3] * rl);
        *(uint2*)&Ob[(size_t)qg * DM + h * 64 + mtd * 16 + quad * 4] =
            make_uint2(lo, hi);
      }
    }
  } else {
    const int ps = (h * 32 + qb) * 4 + c;
#pragma unroll
    for (int nt = 0; nt < 2; ++nt) {
      int q = w * 32 + nt * 16 + ql;
      if (quad == 0) Lpart[ps * 128 + q] = lf[nt];
#pragma unroll
      for (int mtd = 0; mtd < 4; ++mtd) {
        uint32_t lo = pk2(o_acc[mtd][nt][0], o_acc[mtd][nt][1]);
        uint32_t hi = pk2(o_acc[mtd][nt][2], o_acc[mtd][nt][3]);
        *(uint2*)&OpartB[(size_t)ps * 8192 + q * 64 + mtd * 16 + quad * 4] =
            make_uint2(lo, hi);
      }
    }
  }
}

// merge <=4 bf16 partials per (h, qb>=8) -> Ob (fixed base: plain sums)
__global__ __launch_bounds__(256) void combine_kernel(
    const uint16_t* __restrict__ OpartB, const float* __restrict__ Lpart,
    bf16* __restrict__ Ob) {
  int b = blockIdx.x;
  int h = b % NH, qb = 8 + b / NH;
  int nch = (qb + 8) >> 3;  // ceil((qb+1)/8), 2..4
  int t = threadIdx.x;
  int q = t >> 1, dh = (t & 1) * 32;
  int ps0 = (h * 32 + qb) * 4;

  float acc[32] = {};
  float L = 0.f;
#pragma unroll
  for (int cc = 0; cc < 4; ++cc)
    if (cc < nch) {
      L += Lpart[(ps0 + cc) * 128 + q];
      const uint4* p =
          (const uint4*)(OpartB + (size_t)(ps0 + cc) * 8192 + q * 64 + dh);
#pragma unroll
      for (int g = 0; g < 4; ++g) {
        uint4 u = p[g];
        acc[g * 8 + 0] += bflo(u.x); acc[g * 8 + 1] += bfhi(u.x);
        acc[g * 8 + 2] += bflo(u.y); acc[g * 8 + 3] += bfhi(u.y);
        acc[g * 8 + 4] += bflo(u.z); acc[g * 8 + 5] += bfhi(u.z);
        acc[g * 8 + 6] += bflo(u.w); acc[g * 8 + 7] += bfhi(u.w);
      }
    }
  float rl = 1.0f / L;
  bf16* dst = &Ob[(size_t)(qb * 128 + q) * DM + h * 64 + dh];
#pragma unroll
  for (int g = 0; g < 4; ++g) {
    uint4 u;
    u.x = pk2(acc[g * 8 + 0] * rl, acc[g * 8 + 1] * rl);
    u.y = pk2(acc[g * 8 + 2] * rl, acc[g * 8 + 3] * rl);
    u.z = pk2(acc[g * 8 + 4] * rl, acc[g * 8 + 5] * rl);
    u.w = pk2(acc[g * 8 + 6] * rl, acc[g * 8 + 7] * rl);
    *(uint4*)&dst[g * 8] = u;
  }
}

extern "C" void kernel_launch(void* const* d_in, const int* in_sizes, int n_in,
                              void* d_out, int out_size, void* d_ws,
                              size_t ws_size, hipStream_t stream) {
  const float* x  = (const float*)d_in[0];
  const float* wq = (const float*)d_in[1];
  const float* wk = (const float*)d_in[2];
  const float* wv = (const float*)d_in[3];
  const float* wp = (const float*)d_in[4];
  char* ws = (char*)d_ws;
  // Lpart lives in the xb region (dead after qkv; attn writes before combine
  // reads). Peak ws usage = 61341696 B (r5-r8-proven size).
  float* Lpart = (float*)(ws);             // 1536*128*4 = 786432 (inside xb)
  bf16* xb   = (bf16*)(ws);
  bf16* wqb  = (bf16*)(ws + 6291456);
  bf16* wkb  = (bf16*)(ws + 7471104);
  bf16* wvb  = (bf16*)(ws + 8650752);
  bf16* wpb  = (bf16*)(ws + 9830400);
  bf16* Qb   = (bf16*)(ws + 11010048);
  bf16* Kb   = (bf16*)(ws + 17301504);
  bf16* Vtb  = (bf16*)(ws + 23592960);
  bf16* Ob   = (bf16*)(ws + 29884416);
  uint16_t* OpartB = (uint16_t*)(ws + 36175872);  // 1536 x 8192 bf16 -> 61341696

  cvt_kernel<<<5376, 256, 0, stream>>>(x, wq, wk, wv, wp, xb, wqb, wkb, wvb, wpb);
  qkv_kernel<<<dim3(32, 6, 3), 256, 0, stream>>>(xb, wqb, wkb, wvb, Qb, Kb, Vtb);
  attn_kernel<<<960, 256, 0, stream>>>(Qb, Kb, Vtb, OpartB, Lpart, Ob);
  combine_kernel<<<288, 256, 0, stream>>>(OpartB, Lpart, Ob);
  proj_kernel<<<dim3(64, 6), 256, 0, stream>>>(Ob, wpb, (float*)d_out);
}